// Round 5
// baseline (353.822 us; speedup 1.0000x reference)
//
#include <hip/hip_runtime.h>
#include <hip/hip_bf16.h>
#include <stdint.h>

// T=1 => softmax over size-1 axis == 1 => attention output == V; q/k/RoPE dead.
// Pipeline: router -> top-128 -> rms1 -> V=h@wv+bv -> X1=x+V@wo -> rms2 ->
// G,U = h2@{Wg,Wu} (fused dual-B GEMM) -> Mb=silu(G)*U -> out copy/scatter ->
// out[sel] += Mb@Wd.
// GEMM v4: NO LDS, NO BARRIERS. Round-4's nodrain-barrier dbuf failed
// correctness (unverifiable waitcnt semantics around inline-asm barriers);
// instead we delete the cross-wave dependency: every wave loads both A and B
// MFMA fragments directly from global (A: 1 dwordx4/lane; B: 8 strided
// dwords/lane = 4x64B segments/instr), cvt_pk fp32->bf16 in regs, 2-bank
// register rotation (prefetch step k+32 during MFMAs of step k). B is read 2x
// per block (wm pair) -- absorbed by L1/L2. Split-K via fp32 atomics.

#define D_ 2048
#define I_ 5504
#define NROWS 256
#define KSEL 128

typedef __attribute__((ext_vector_type(8))) short short8;   // 8 x bf16
typedef __attribute__((ext_vector_type(4))) float floatx4;  // MFMA acc

__device__ __forceinline__ unsigned short f2bf(float f) {
  union { float f; unsigned int u; } v; v.f = f;
  unsigned int r = (v.u + 0x7FFFu + ((v.u >> 16) & 1u)) >> 16;  // RNE
  return (unsigned short)r;
}

__device__ __forceinline__ unsigned int pk2(float lo, float hi) {
  __hip_bfloat162 h = __float22bfloat162_rn(float2{lo, hi});  // v_cvt_pk_bf16_f32
  unsigned int u; __builtin_memcpy(&u, &h, 4); return u;
}

// ---------------- K1: router scores ----------------
__global__ void k_router(const float* __restrict__ hid, const float* __restrict__ rw,
                         const float* __restrict__ rb, float* __restrict__ scores) {
  int b = blockIdx.x, t = threadIdx.x;
  const float* x = hid + (size_t)b * D_;
  float s = 0.f;
  for (int i = t; i < D_; i += 256) s += x[i] * rw[i];
  for (int o = 32; o; o >>= 1) s += __shfl_down(s, o);
  __shared__ float red[4];
  if ((t & 63) == 0) red[t >> 6] = s;
  __syncthreads();
  if (t == 0) scores[b] = red[0] + red[1] + red[2] + red[3] + rb[0];
}

// ---------------- K2: exact top-k, deterministic (rank == slot) ----------------
__global__ void k_select(const float* __restrict__ scores, const int* __restrict__ kptr,
                         int* __restrict__ sel, int* __restrict__ pos) {
  __shared__ float sv[NROWS];
  int t = threadIdx.x;
  sv[t] = scores[t];
  __syncthreads();
  float s = sv[t];
  int c = 0;
  for (int j = 0; j < NROWS; ++j) {
    float o = sv[j];
    c += (o > s) || (o == s && j < t);
  }
  int k = *kptr;                 // k_sel == 128 (grids sized for it)
  if (c < k) sel[c] = t;
  pos[t] = (c < k) ? c : -1;
}

// ---------------- K3: rms1, init V=bv, X1=x, H bf16 ----------------
__global__ void k_rms1(const float* __restrict__ hid, const int* __restrict__ sel,
                       const float* __restrict__ ln1, const float* __restrict__ bv,
                       unsigned short* __restrict__ Hb, float* __restrict__ V,
                       float* __restrict__ X1) {
  int i = blockIdx.x, t = threadIdx.x;
  int r = sel[i];
  const float* x = hid + (size_t)r * D_;
  float xs[8]; float ss = 0.f;
#pragma unroll
  for (int c = 0; c < 8; ++c) { float v = x[t + c * 256]; xs[c] = v; ss += v * v; }
  for (int o = 32; o; o >>= 1) ss += __shfl_down(ss, o);
  __shared__ float red[4];
  if ((t & 63) == 0) red[t >> 6] = ss;
  __syncthreads();
  float inv = rsqrtf((red[0] + red[1] + red[2] + red[3]) * (1.0f / D_) + 1e-6f);
#pragma unroll
  for (int c = 0; c < 8; ++c) {
    int idx = t + c * 256;
    size_t o_ = (size_t)i * D_ + idx;
    Hb[o_] = f2bf(xs[c] * inv * ln1[idx]);
    V[o_] = bv[idx];
    X1[o_] = xs[c];
  }
}

// ---------------- K5: rms2, zero G/U ----------------
__global__ void k_rms2(const float* __restrict__ X1, const float* __restrict__ ln2,
                       unsigned short* __restrict__ H2b, float* __restrict__ G,
                       float* __restrict__ U) {
  int i = blockIdx.x, t = threadIdx.x;
  const float* x = X1 + (size_t)i * D_;
  float xs[8]; float ss = 0.f;
#pragma unroll
  for (int c = 0; c < 8; ++c) { float v = x[t + c * 256]; xs[c] = v; ss += v * v; }
  for (int o = 32; o; o >>= 1) ss += __shfl_down(ss, o);
  __shared__ float red[4];
  if ((t & 63) == 0) red[t >> 6] = ss;
  __syncthreads();
  float inv = rsqrtf((red[0] + red[1] + red[2] + red[3]) * (1.0f / D_) + 1e-6f);
#pragma unroll
  for (int c = 0; c < 8; ++c) {
    int idx = t + c * 256;
    H2b[(size_t)i * D_ + idx] = f2bf(xs[c] * inv * ln2[idx]);
  }
  for (int j = t; j < I_; j += 256) {
    G[(size_t)i * I_ + j] = 0.f;
    U[(size_t)i * I_ + j] = 0.f;
  }
}

// ---------------- K7: Mb = silu(G)*U ; out = copy/scatter ----------------
__global__ void k_silu_out(const float* __restrict__ G, const float* __restrict__ U,
                           unsigned short* __restrict__ Mb,
                           const float* __restrict__ X1, const int* __restrict__ pos,
                           const float* __restrict__ hid, float* __restrict__ out) {
  int tid = blockIdx.x * 256 + threadIdx.x;
  int stride = gridDim.x * 256;
  const int nM = KSEL * I_;    // 704512
  for (int i = tid; i < nM; i += stride) {
    float g = G[i], u = U[i];
    float m = (g / (1.f + expf(-g))) * u;
    Mb[i] = f2bf(m);
  }
  const int nO4 = NROWS * (D_ / 4);   // 131072 float4
  const float4* X14 = (const float4*)X1;
  const float4* H4 = (const float4*)hid;
  float4* O4 = (float4*)out;
  for (int i = tid; i < nO4; i += stride) {
    int row = i >> 9;             // 512 float4 per row
    int c4 = i & 511;
    int p = pos[row];
    O4[i] = (p >= 0) ? X14[(size_t)p * 512 + c4] : H4[i];
  }
}

// ---------------- GEMM: C[128xN] += A[128xKA] @ B[KbxN] ----------------
// Block tile 128m x 32n, 4 waves (wm = 64-row half, wn = 16-col half).
// Per 32-deep K-step, per lane: A = 4 x short8 direct global loads
// (A[m=lane&15][k=(lane>>4)*8+j] fragment layout, proven R3); B = 8 strided
// dwords (col n = wn*16+fm fixed, rows k..k+7 by quad) packed via cvt_pk to
// the B fragment. Two register banks rotate: bank for step s+1 loads before
// MFMAs of step s. No LDS, no barriers. K (iteration space, multiple of 64)
// may exceed KA: A chunks >= KA read as zero, B rows clamped to Kb-1
// (multiplied by zero A). AF32: A is fp32 (wo GEMM). DUAL: gate+up pair.
template<bool AF32, bool DUAL>
__global__ __launch_bounds__(256)
void k_gemm(const void* __restrict__ Ap, const float* __restrict__ B0,
            const float* __restrict__ B1, float* __restrict__ C0,
            float* __restrict__ C1, const int* __restrict__ rowmap,
            int K, int KA, int Kb, int lda, int N, int KT, int ldc) {
  const int bn = blockIdx.x;
  const int kt0 = blockIdx.y * KT;
  const int kt1 = kt0 + KT;
  const int tid = threadIdx.x;
  const int lane = tid & 63;
  const int wave = tid >> 6;
  const int wm = wave >> 1, wn = wave & 1;
  const int fm = lane & 15, kq = lane >> 4;

  floatx4 acc0[4] = {};
  floatx4 acc1[4] = {};

  // A fragment base: row = wm*64 + i*16 + fm, k = kt + kq*8 + j
  const unsigned short* Ab_lane = AF32 ? nullptr
      : (const unsigned short*)Ap + (size_t)(wm * 64 + fm) * lda + kq * 8;
  const float* Af_lane = AF32
      ? (const float*)Ap + (size_t)(wm * 64 + fm) * lda + kq * 8 : nullptr;
  // B fragment column: n = bn*32 + wn*16 + fm ; rows k = kt + kq*8 + j
  const float* B0c = B0 + (size_t)(bn * 32 + wn * 16 + fm);
  const float* B1c = DUAL ? B1 + (size_t)(bn * 32 + wn * 16 + fm) : nullptr;

  // two register banks for the k-step rotation
  short8 aR[2][4];
  float4 aF[2][8];
  float  bR0[2][8], bR1[2][8];

  auto loadStep = [&](int bk, int kt) {
    if (AF32) {
#pragma unroll
      for (int i = 0; i < 4; ++i) {
        const float* ap = Af_lane + (size_t)i * 16 * lda + kt;
        aF[bk][2 * i]     = *(const float4*)ap;
        aF[bk][2 * i + 1] = *(const float4*)(ap + 4);
      }
    } else {
#pragma unroll
      for (int i = 0; i < 4; ++i) {
        aR[bk][i] = short8{};
        if (kt + kq * 8 < KA)
          aR[bk][i] = *(const short8*)(Ab_lane + (size_t)i * 16 * lda + kt);
      }
    }
#pragma unroll
    for (int j = 0; j < 8; ++j) {
      int kr = kt + kq * 8 + j; kr = kr < Kb ? kr : Kb - 1;
      bR0[bk][j] = B0c[(size_t)kr * N];
      if (DUAL) bR1[bk][j] = B1c[(size_t)kr * N];
    }
  };

  auto computeStep = [&](int bk) {
    union { short8 s; unsigned int u[4]; } b0, b1;
    b0.u[0] = pk2(bR0[bk][0], bR0[bk][1]); b0.u[1] = pk2(bR0[bk][2], bR0[bk][3]);
    b0.u[2] = pk2(bR0[bk][4], bR0[bk][5]); b0.u[3] = pk2(bR0[bk][6], bR0[bk][7]);
    if (DUAL) {
      b1.u[0] = pk2(bR1[bk][0], bR1[bk][1]); b1.u[1] = pk2(bR1[bk][2], bR1[bk][3]);
      b1.u[2] = pk2(bR1[bk][4], bR1[bk][5]); b1.u[3] = pk2(bR1[bk][6], bR1[bk][7]);
    }
#pragma unroll
    for (int i = 0; i < 4; ++i) {
      short8 a;
      if (AF32) {
        union { short8 s; unsigned int u[4]; } p;
        float4 x0 = aF[bk][2 * i], x1 = aF[bk][2 * i + 1];
        p.u[0] = pk2(x0.x, x0.y); p.u[1] = pk2(x0.z, x0.w);
        p.u[2] = pk2(x1.x, x1.y); p.u[3] = pk2(x1.z, x1.w);
        a = p.s;
      } else {
        a = aR[bk][i];
      }
      acc0[i] = __builtin_amdgcn_mfma_f32_16x16x32_bf16(a, b0.s, acc0[i], 0, 0, 0);
      if (DUAL)
        acc1[i] = __builtin_amdgcn_mfma_f32_16x16x32_bf16(a, b1.s, acc1[i], 0, 0, 0);
    }
  };

  // software pipeline: bank b holds step kt, other bank prefetches kt+32
  loadStep(0, kt0);
  int kt = kt0;
  for (; kt + 64 < kt1; kt += 64) {
    loadStep(1, kt + 32);
    computeStep(0);
    loadStep(0, kt + 64);
    computeStep(1);
  }
  loadStep(1, kt + 32);   // KT % 64 == 0 -> exactly two steps remain
  computeStep(0);
  computeStep(1);

  // epilogue: atomic accumulate (C/D layout: col=lane&15, row=(lane>>4)*4+reg)
#pragma unroll
  for (int i = 0; i < 4; ++i) {
#pragma unroll
    for (int r = 0; r < 4; ++r) {
      int row = wm * 64 + i * 16 + kq * 4 + r;
      size_t rbase = rowmap ? (size_t)rowmap[row] * ldc : (size_t)row * ldc;
      int col = bn * 32 + wn * 16 + fm;
      atomicAdd(&C0[rbase + col], acc0[i][r]);
      if (DUAL) atomicAdd(&C1[rbase + col], acc1[i][r]);
    }
  }
}

extern "C" void kernel_launch(void* const* d_in, const int* in_sizes, int n_in,
                              void* d_out, int out_size, void* d_ws, size_t ws_size,
                              hipStream_t stream) {
  const float* hid = (const float*)d_in[0];
  const float* rw  = (const float*)d_in[3];
  const float* rb  = (const float*)d_in[4];
  const float* ln1 = (const float*)d_in[5];
  const float* ln2 = (const float*)d_in[6];
  const float* wv  = (const float*)d_in[11];
  const float* bv  = (const float*)d_in[12];
  const float* wo  = (const float*)d_in[13];
  const float* wg  = (const float*)d_in[14];
  const float* wu  = (const float*)d_in[15];
  const float* wd  = (const float*)d_in[16];
  const int*   kp  = (const int*)d_in[17];
  float* out = (float*)d_out;

  char* ws = (char*)d_ws;
  float*          scores = (float*)(ws + 0);           // 1 KB
  int*            sel    = (int*)(ws + 1024);          // 512 B
  int*            pos    = (int*)(ws + 1536);          // 1 KB
  unsigned short* Hb     = (unsigned short*)(ws + 4096);        // 512 KB
  float*          V      = (float*)(ws + 528384);      // 1 MB
  float*          X1     = (float*)(ws + 1576960);     // 1 MB
  unsigned short* H2b    = (unsigned short*)(ws + 2625536);     // 512 KB
  float*          G      = (float*)(ws + 3149824);     // 2.69 MB
  float*          U      = (float*)(ws + 5967872);     // 2.69 MB
  unsigned short* Mb     = (unsigned short*)(ws + 8785920);     // 1.34 MB

  k_router<<<256, 256, 0, stream>>>(hid, rw, rb, scores);
  k_select<<<1, 256, 0, stream>>>(scores, kp, sel, pos);
  k_rms1<<<128, 256, 0, stream>>>(hid, sel, ln1, bv, Hb, V, X1);
  // V += Hb @ wv   (64 n-tiles x 8 splits, KT=256)
  k_gemm<false, false><<<dim3(64, 8), 256, 0, stream>>>(
      Hb, wv, nullptr, V, nullptr, nullptr, 2048, 2048, 2048, 2048, 2048, 256, 2048);
  // X1 += V @ wo  (A fp32)
  k_gemm<true, false><<<dim3(64, 8), 256, 0, stream>>>(
      V, wo, nullptr, X1, nullptr, nullptr, 2048, 2048, 2048, 2048, 2048, 256, 2048);
  k_rms2<<<128, 256, 0, stream>>>(X1, ln2, H2b, G, U);
  // G,U += H2b @ {wg,wu}  (172 n-tiles x 4 splits, KT=512)
  k_gemm<false, true><<<dim3(172, 4), 256, 0, stream>>>(
      H2b, wg, wu, G, U, nullptr, 2048, 2048, 2048, 2048, 5504, 512, 5504);
  k_silu_out<<<1024, 256, 0, stream>>>(G, U, Mb, X1, pos, hid, out);
  // out[sel] += Mb @ wd  (64 n-tiles x 8 splits, KT=704 -> K padded 5504->5632)
  k_gemm<false, false><<<dim3(64, 8), 256, 0, stream>>>(
      Mb, wd, nullptr, out, nullptr, sel, 5632, 5504, 5504, 5504, 2048, 704, 2048);
}